// Round 1
// baseline (87.586 us; speedup 1.0000x reference)
//
#include <hip/hip_runtime.h>

// Problem constants (match reference)
#define NB 16      // BATCH
#define NC 32      // IN_CH
#define NO 32      // OUT_CH
#define NM 1024    // NODES
#define SEGS 32
#define WLEN 97    // (N-1)*SEGMENTS + 1

// ---------------------------------------------------------------------------
// Repack w[o][c][0..96] -> w2[o][c][seg] = float4(w[3seg], w[3seg+1], w[3seg+2], w[3seg+3])
// 32*32*32 = 32768 float4 = 512 KB, aligned 16B loads afterwards.
// ---------------------------------------------------------------------------
__global__ __launch_bounds__(256) void repack_w_kernel(const float* __restrict__ w,
                                                       float4* __restrict__ w2) {
    int i = blockIdx.x * blockDim.x + threadIdx.x;   // 0 .. 32767
    if (i >= NO * NC * SEGS) return;
    int seg = i & (SEGS - 1);
    int oc  = i >> 5;                                 // o*32 + c
    const float* p = w + oc * WLEN + 3 * seg;
    w2[i] = make_float4(p[0], p[1], p[2], p[3]);
}

// ---------------------------------------------------------------------------
// Main kernel. Block = (b, tile of 8 nodes), covering all 32 out-channels.
//   threads 256 = 32 o  x 8 m
// Phase 1: 32c x 8m basis + segment index into LDS (one element per thread).
// Phase 2: each thread computes one output (b, o, m): sum over c of
//          dot(basis4, w2[o][c][seg]).
// ---------------------------------------------------------------------------
template <bool USE_W2>
__global__ __launch_bounds__(256) void pw_main_kernel(const float* __restrict__ x,
                                                      const float* __restrict__ w,
                                                      const float4* __restrict__ w2,
                                                      float* __restrict__ out) {
    const int blk = blockIdx.x;          // 0 .. 2047
    const int b   = blk >> 7;            // 16 batches
    const int m0  = (blk & 127) * 8;     // node-tile base

    __shared__ float4 sb[NC][8];         // basis, 4 KB
    __shared__ int    sseg[NC][8];       // segment ids, 1 KB

    const int tid = threadIdx.x;

    // ---- phase 1: basis + segment for this (b, m-tile), one (c, mt) per thread
    {
        const int c  = tid >> 3;
        const int mt = tid & 7;
        const float xv = x[(b * NC + c) * NM + m0 + mt];

        // id = clip(trunc((x+1)/2*32), 0, 31); (x+1)*16 is bit-exact equal.
        float v  = (xv + 1.0f) * 16.0f;
        int   id = (int)v;               // trunc-toward-zero == astype(int32)
        id = min(max(id, 0), SEGS - 1);

        // x_in = 32*(x - x_min) - 1, x_min = id/16 - 1 (exact)
        const float x_min = (float)id * 0.0625f - 1.0f;
        const float t     = (xv - x_min) * 32.0f - 1.0f;

        // Lagrange basis at Chebyshev points X = {-1, -0.5, 0.5, 1}
        const float d0 = t + 1.0f;
        const float d1 = t + 0.5f;
        const float d2 = t - 0.5f;
        const float d3 = t - 1.0f;
        float4 bb;
        bb.x = d1 * d2 * d3 * (-0.66666667f);  // denom -1.5
        bb.y = d0 * d2 * d3 * ( 1.33333333f);  // denom  0.75
        bb.z = d0 * d1 * d3 * (-1.33333333f);  // denom -0.75
        bb.w = d0 * d1 * d2 * ( 0.66666667f);  // denom  1.5

        sb[c][mt]   = bb;
        sseg[c][mt] = id;
    }
    __syncthreads();

    // ---- phase 2: one output per thread
    const int o  = tid >> 3;
    const int mt = tid & 7;

    float acc = 0.0f;
#pragma unroll
    for (int c = 0; c < NC; ++c) {
        const float4 bb = sb[c][mt];         // 8-way same-address broadcast
        const int    sg = sseg[c][mt];
        float4 wv;
        if (USE_W2) {
            wv = w2[(o * NC + c) * SEGS + sg];
        } else {
            const float* p = w + (o * NC + c) * WLEN + 3 * sg;
            wv = make_float4(p[0], p[1], p[2], p[3]);
        }
        acc = fmaf(bb.x, wv.x, acc);
        acc = fmaf(bb.y, wv.y, acc);
        acc = fmaf(bb.z, wv.z, acc);
        acc = fmaf(bb.w, wv.w, acc);
    }

    out[(b * NO + o) * NM + m0 + mt] = acc;
}

extern "C" void kernel_launch(void* const* d_in, const int* in_sizes, int n_in,
                              void* d_out, int out_size, void* d_ws, size_t ws_size,
                              hipStream_t stream) {
    const float* x = (const float*)d_in[0];   // (16, 32, 1024)
    const float* w = (const float*)d_in[1];   // (32, 32, 97)
    float* out = (float*)d_out;               // (16, 32, 1024)

    const size_t w2_bytes = (size_t)NO * NC * SEGS * sizeof(float4);  // 512 KB

    if (ws_size >= w2_bytes) {
        float4* w2 = (float4*)d_ws;
        repack_w_kernel<<<(NO * NC * SEGS + 255) / 256, 256, 0, stream>>>(w, w2);
        pw_main_kernel<true><<<NB * (NM / 8), 256, 0, stream>>>(x, w, w2, out);
    } else {
        pw_main_kernel<false><<<NB * (NM / 8), 256, 0, stream>>>(x, w, nullptr, out);
    }
}

// Round 2
// 67.893 us; speedup vs baseline: 1.2900x; 1.2900x over previous
//
#include <hip/hip_runtime.h>

// Problem constants (match reference)
#define NB 16      // BATCH
#define NC 32      // IN_CH
#define NO 32      // OUT_CH
#define NM 1024    // NODES
#define SEGS 32
#define WLEN 97    // (N-1)*SEGMENTS + 1

// ---------------------------------------------------------------------------
// Repack w[o][c][0..96] -> w3[c][seg][o] = float4(w[o][c][3seg .. 3seg+3])
// 32*32*32 float4 = 512 KB. Layout puts o innermost so the main kernel's
// gather is fully coalesced (32 lanes x 16B = 512B contiguous per (c,seg)).
// ---------------------------------------------------------------------------
__global__ __launch_bounds__(256) void repack_w_kernel(const float* __restrict__ w,
                                                       float4* __restrict__ w3) {
    int i = blockIdx.x * blockDim.x + threadIdx.x;   // 0 .. 32767
    if (i >= NC * SEGS * NO) return;
    int o   = i & 31;
    int seg = (i >> 5) & 31;
    int c   = i >> 10;
    const float* p = w + (o * NC + c) * WLEN + 3 * seg;
    w3[i] = make_float4(p[0], p[1], p[2], p[3]);
}

// ---------------------------------------------------------------------------
// Main kernel. Block = (b, tile of 8 nodes), 256 threads.
// Phase 1: 32c x 8m basis + segment into LDS (one (c,mt) per thread).
// Phase 2: thread = (o = tid&31, mt = tid>>5). Per c: LDS broadcast of
//          basis4/seg (same addr for 32 o-lanes), coalesced 512B gather of
//          w3[c][sg][o..o+31], 4 FMA.
// ---------------------------------------------------------------------------
template <bool USE_W3>
__global__ __launch_bounds__(256) void pw_main_kernel(const float* __restrict__ x,
                                                      const float* __restrict__ w,
                                                      const float4* __restrict__ w3,
                                                      float* __restrict__ out) {
    const int blk = blockIdx.x;          // 0 .. 2047
    const int b   = blk >> 7;            // 16 batches
    const int m0  = (blk & 127) * 8;     // node-tile base

    __shared__ float4 sb[NC][8];         // basis, 4 KB
    __shared__ int    sseg[NC][8];       // segment ids, 1 KB

    const int tid = threadIdx.x;

    // ---- phase 1: basis + segment for this (b, m-tile)
    {
        const int c  = tid >> 3;
        const int mt = tid & 7;
        const float xv = x[(b * NC + c) * NM + m0 + mt];

        // id = clip(trunc((x+1)/2*32), 0, 31); (x+1)*16 is bit-exact equal.
        float v  = (xv + 1.0f) * 16.0f;
        int   id = (int)v;               // trunc-toward-zero == astype(int32)
        id = min(max(id, 0), SEGS - 1);

        // x_in = 32*(x - x_min) - 1, x_min = id/16 - 1 (exact)
        const float x_min = (float)id * 0.0625f - 1.0f;
        const float t     = (xv - x_min) * 32.0f - 1.0f;

        // Lagrange basis at Chebyshev points X = {-1, -0.5, 0.5, 1}
        const float d0 = t + 1.0f;
        const float d1 = t + 0.5f;
        const float d2 = t - 0.5f;
        const float d3 = t - 1.0f;
        float4 bb;
        bb.x = d1 * d2 * d3 * (-0.66666667f);  // denom -1.5
        bb.y = d0 * d2 * d3 * ( 1.33333333f);  // denom  0.75
        bb.z = d0 * d1 * d3 * (-1.33333333f);  // denom -0.75
        bb.w = d0 * d1 * d2 * ( 0.66666667f);  // denom  1.5

        sb[c][mt]   = bb;
        sseg[c][mt] = id;
    }
    __syncthreads();

    // ---- phase 2: one output per thread; o innermost across lanes
    const int o  = tid & 31;
    const int mt = tid >> 5;

    float acc = 0.0f;
#pragma unroll
    for (int c = 0; c < NC; ++c) {
        const float4 bb = sb[c][mt];         // 32-lane same-address broadcast
        const int    sg = sseg[c][mt];
        float4 wv;
        if (USE_W3) {
            wv = w3[(c * SEGS + sg) * NO + o];   // coalesced: 512B per 32 lanes
        } else {
            const float* p = w + (o * NC + c) * WLEN + 3 * sg;
            wv = make_float4(p[0], p[1], p[2], p[3]);
        }
        acc = fmaf(bb.x, wv.x, acc);
        acc = fmaf(bb.y, wv.y, acc);
        acc = fmaf(bb.z, wv.z, acc);
        acc = fmaf(bb.w, wv.w, acc);
    }

    out[(b * NO + o) * NM + m0 + mt] = acc;
}

extern "C" void kernel_launch(void* const* d_in, const int* in_sizes, int n_in,
                              void* d_out, int out_size, void* d_ws, size_t ws_size,
                              hipStream_t stream) {
    const float* x = (const float*)d_in[0];   // (16, 32, 1024)
    const float* w = (const float*)d_in[1];   // (32, 32, 97)
    float* out = (float*)d_out;               // (16, 32, 1024)

    const size_t w3_bytes = (size_t)NC * SEGS * NO * sizeof(float4);  // 512 KB

    if (ws_size >= w3_bytes) {
        float4* w3 = (float4*)d_ws;
        repack_w_kernel<<<(NC * SEGS * NO + 255) / 256, 256, 0, stream>>>(w, w3);
        pw_main_kernel<true><<<NB * (NM / 8), 256, 0, stream>>>(x, w, w3, out);
    } else {
        pw_main_kernel<false><<<NB * (NM / 8), 256, 0, stream>>>(x, w, nullptr, out);
    }
}